// Round 4
// baseline (2473.994 us; speedup 1.0000x reference)
//
#include <hip/hip_runtime.h>
#include <stdint.h>

// VQ-VAE codebook argmin, f32 in / f32 out (established R2/R3).
// Ref mimicry: d2 computed by numpy in f32 => quantized at ulp(||z||^2~512)=3-6e-5;
// argmin ties in the same f32 bin break to the SMALLER index. We emulate numpy's
// exact f32 arithmetic (pairwise sums + SSE einsum loop) over GEMM-selected candidates.

#define B_ROWS 32768
#define DIM    512
#define KCODES 8192
#define SUPERS 2
#define TILES  32   // 2 supers * 32 tiles * 128 = 8192 codes

typedef short bhalf8_t __attribute__((ext_vector_type(8)));
typedef float f32x4_t  __attribute__((ext_vector_type(4)));

__device__ __forceinline__ float b2f(unsigned short u) {
    return __uint_as_float(((unsigned int)u) << 16);
}
__device__ __forceinline__ unsigned short f2b(float f) {  // RNE
    unsigned int x = __float_as_uint(f);
    return (unsigned short)((x + 0x7FFFu + ((x >> 16) & 1u)) >> 16);
}

// ---------- K1: numpy-pairwise-emulated row sum of squares ----------
// np pairwise, n=512: (S0+S1)+(S2+S3); each S = 128-block with 8 accumulators
// r[j] (stride 8, 16 sequential adds), combined ((r0+r1)+(r2+r3))+((r4+r5)+(r6+r7)).
__global__ __launch_bounds__(256) void k_pairsq(const float* __restrict__ X,
                                                float* __restrict__ out, int nrows) {
    int wid = threadIdx.x >> 6, lane = threadIdx.x & 63;
    int r = blockIdx.x * 4 + wid;
    if (r >= nrows) return;
    int b = lane >> 3, j = lane & 7;   // b: 128-block (0..3 used), j: accumulator
    float acc = 0.f;
    if (b < 4) {
        const float* x = X + (size_t)r * DIM + b * 128 + j;
        float v = x[0];
        acc = __fmul_rn(v, v);
        for (int i = 1; i < 16; i++) {
            float w = x[8 * i];
            acc = __fadd_rn(acc, __fmul_rn(w, w));
        }
    }
    // j-tree: ((r0+r1)+(r2+r3))+((r4+r5)+(r6+r7))
    float t = __fadd_rn(acc, __shfl_xor(acc, 1));
    t = __fadd_rn(t, __shfl_xor(t, 2));
    t = __fadd_rn(t, __shfl_xor(t, 4));
    // block tree: (S0+S1)+(S2+S3)  (S_b lives on lanes 0,8,16,24)
    float u = __fadd_rn(t, __shfl_xor(t, 8));
    u = __fadd_rn(u, __shfl_xor(u, 16));
    if (lane == 0) out[r] = u;
}

// ---------- K2: GEMM (split-bf16 3-MFMA) + per-(row,slice) top-2 -> top-8/super ----------
__global__ __launch_bounds__(256) void k_argmin(const float* __restrict__ Zf,
                                                const float* __restrict__ Wf,
                                                const float* __restrict__ c32,
                                                float2* __restrict__ part) {
    __shared__ alignas(16) unsigned char smem[32768];
    const int tid = threadIdx.x;
    const int lane = tid & 63, w = tid >> 6;
    const int wm = w >> 1, wn = w & 1;
    const int lane15 = lane & 15, q = lane >> 4;
    const int rb = blockIdx.x * 128;
    const int super = blockIdx.y;

    float v1a[4][4], v2a[4][4];
    int   n1a[4][4], n2a[4][4];
#pragma unroll
    for (int i = 0; i < 4; i++)
#pragma unroll
        for (int jj = 0; jj < 4; jj++) {
            v1a[i][jj] = 3.4e38f; v2a[i][jj] = 3.4e38f;
            n1a[i][jj] = 0x7FFFFFFF; n2a[i][jj] = 0x7FFFFFFF;
        }

    for (int tl = 0; tl < TILES; ++tl) {
        const int nt = (super * TILES + tl) * 128;
        f32x4_t acc[4][4];
#pragma unroll
        for (int i = 0; i < 4; i++)
#pragma unroll
            for (int jj = 0; jj < 4; jj++) acc[i][jj] = (f32x4_t){0.f, 0.f, 0.f, 0.f};

        for (int kb = 0; kb < DIM; kb += 32) {
            __syncthreads();
#pragma unroll
            for (int i = 0; i < 4; i++) {
                int t = i * 256 + tid;
                int row = t >> 3, seg = t & 7;     // 8 float4 per 32-f32 row
                float4 a = *(const float4*)(Zf + (size_t)(rb + row) * DIM + kb + seg * 4);
                float4 b = *(const float4*)(Wf + (size_t)(nt + row) * DIM + kb + seg * 4);
                unsigned short ah0 = f2b(a.x), ah1 = f2b(a.y), ah2 = f2b(a.z), ah3 = f2b(a.w);
                unsigned short bh0 = f2b(b.x), bh1 = f2b(b.y), bh2 = f2b(b.z), bh3 = f2b(b.w);
                unsigned short al0 = f2b(a.x - b2f(ah0)), al1 = f2b(a.y - b2f(ah1));
                unsigned short al2 = f2b(a.z - b2f(ah2)), al3 = f2b(a.w - b2f(ah3));
                unsigned short bl0 = f2b(b.x - b2f(bh0)), bl1 = f2b(b.y - b2f(bh1));
                unsigned short bl2 = f2b(b.z - b2f(bh2)), bl3 = f2b(b.w - b2f(bh3));
                int o = row * 64 + seg * 8;
                *(uint2*)(smem +         o) = make_uint2((unsigned)ah0 | ((unsigned)ah1 << 16), (unsigned)ah2 | ((unsigned)ah3 << 16));
                *(uint2*)(smem +  8192 + o) = make_uint2((unsigned)bh0 | ((unsigned)bh1 << 16), (unsigned)bh2 | ((unsigned)bh3 << 16));
                *(uint2*)(smem + 16384 + o) = make_uint2((unsigned)al0 | ((unsigned)al1 << 16), (unsigned)al2 | ((unsigned)al3 << 16));
                *(uint2*)(smem + 24576 + o) = make_uint2((unsigned)bl0 | ((unsigned)bl1 << 16), (unsigned)bl2 | ((unsigned)bl3 << 16));
            }
            __syncthreads();

            bhalf8_t ah[4], bh[4], al[4], bl[4];
#pragma unroll
            for (int f = 0; f < 4; f++) {
                int off = (f * 16 + lane15) * 64 + q * 16;
                ah[f] = *(const bhalf8_t*)(smem +         (wm * 4096 + off));
                bh[f] = *(const bhalf8_t*)(smem +  8192 + (wn * 4096 + off));
                al[f] = *(const bhalf8_t*)(smem + 16384 + (wm * 4096 + off));
                bl[f] = *(const bhalf8_t*)(smem + 24576 + (wn * 4096 + off));
            }
#pragma unroll
            for (int fm = 0; fm < 4; fm++)
#pragma unroll
                for (int fn = 0; fn < 4; fn++) {
                    acc[fm][fn] = __builtin_amdgcn_mfma_f32_16x16x32_bf16(al[fm], bh[fn], acc[fm][fn], 0, 0, 0);
                    acc[fm][fn] = __builtin_amdgcn_mfma_f32_16x16x32_bf16(ah[fm], bl[fn], acc[fm][fn], 0, 0, 0);
                    acc[fm][fn] = __builtin_amdgcn_mfma_f32_16x16x32_bf16(ah[fm], bh[fn], acc[fm][fn], 0, 0, 0);
                }
        }

        // epilogue: s = c[n] - 2*dot ; per-(row-slot, slice) top-2 insert
        float cf[4]; int nb[4];
#pragma unroll
        for (int fn = 0; fn < 4; fn++) {
            nb[fn] = nt + wn * 64 + fn * 16 + lane15;
            cf[fn] = c32[nb[fn]];
        }
#pragma unroll
        for (int fm = 0; fm < 4; fm++)
#pragma unroll
            for (int r = 0; r < 4; r++)
#pragma unroll
                for (int fn = 0; fn < 4; fn++) {   // ascending n => smallest-n wins ties
                    float sv = fmaf(-2.0f, acc[fm][fn][r], cf[fn]);
                    if (sv < v1a[fm][r]) {
                        v2a[fm][r] = v1a[fm][r]; n2a[fm][r] = n1a[fm][r];
                        v1a[fm][r] = sv;         n1a[fm][r] = nb[fn];
                    } else if (sv < v2a[fm][r]) {
                        v2a[fm][r] = sv; n2a[fm][r] = nb[fn];
                    }
                }
    }

    // per-row top-8 via LDS, two 64-row halves (half == wm)
    float* evv = (float*)smem;   // [64 rows][32 slices][2 slots][2 floats] = 32 KB
    for (int half = 0; half < 2; half++) {
        __syncthreads();
        if (wm == half) {
#pragma unroll
            for (int fm = 0; fm < 4; fm++)
#pragma unroll
                for (int r = 0; r < 4; r++) {
                    int rl = fm * 16 + q * 4 + r;        // local row 0..63
                    int slice = wn * 16 + lane15;
                    int base = (rl * 32 + slice) * 4;
                    evv[base + 0] = v1a[fm][r];
                    evv[base + 1] = __int_as_float(n1a[fm][r]);
                    evv[base + 2] = v2a[fm][r];
                    evv[base + 3] = __int_as_float(n2a[fm][r]);
                }
        }
        __syncthreads();
        if (tid < 64) {
            int rl = tid;
            int rglob = rb + half * 64 + rl;
            for (int s = 0; s < 8; s++) {
                float bv = 3.4e38f; int bn = 0x7FFFFFFF; int be = -1;
                for (int e = 0; e < 64; e++) {
                    int a = (rl * 32 + (e >> 1)) * 4 + (e & 1) * 2;
                    float v = evv[a]; int n = __float_as_int(evv[a + 1]);
                    if (v < bv || (v == bv && n < bn)) { bv = v; bn = n; be = e; }
                }
                part[((size_t)rglob * SUPERS + super) * 8 + s] =
                    make_float2(bv, __int_as_float(bn));
                evv[(rl * 32 + (be >> 1)) * 4 + (be & 1) * 2] = 3.4e38f;  // consume
            }
        }
    }
}

// ---------- K3: exact numpy-f32 re-rank of 16 candidates, outputs ----------
__global__ __launch_bounds__(256) void k_exact(const float* __restrict__ Zf,
                                               const float* __restrict__ Wf,
                                               const float2* __restrict__ part,
                                               const float* __restrict__ zz,
                                               const float* __restrict__ ww,
                                               float* __restrict__ outf,
                                               float* __restrict__ lossp) {
    __shared__ float wsum[4];
    int wid = threadIdx.x >> 6, lane = threadIdx.x & 63;
    int r = blockIdx.x * 4 + wid;
    int c = lane >> 2, j = lane & 3;   // candidate 0..15, SSE lane 0..3

    float2 P = part[((size_t)r * SUPERS + (c >> 3)) * 8 + (c & 7)];
    int n = __float_as_int(P.y);
    n = min(max(n, 0), KCODES - 1);

    // numpy einsum baseline-SIMD emulation: 4 stride-4 f32 accumulators (mul+add, no FMA)
    const float* zp = Zf + (size_t)r * DIM + j;
    const float* wp = Wf + (size_t)n * DIM + j;
    float acc = 0.f;
    for (int i = 0; i < 128; i++)
        acc = __fadd_rn(acc, __fmul_rn(zp[4 * i], wp[4 * i]));
    // SSE3 hadd horizontal: (A0+A1)+(A2+A3)
    float t = __fadd_rn(acc, __shfl_xor(acc, 1));
    t = __fadd_rn(t, __shfl_xor(t, 2));
    float dot = __shfl(t, c * 4);      // broadcast group-lane-0 value

    // d2 = fl( fl(zz+ww) - fl(2*dot) )
    float t1 = __fadd_rn(zz[r], ww[n]);
    float t2 = __fmul_rn(2.0f, dot);
    float d2 = __fadd_rn(t1, -t2);

    float bd = (j == 0) ? d2 : 3.4e38f;
    int   bn = (j == 0) ? n  : 0x7FFFFFFF;
#pragma unroll
    for (int off = 32; off; off >>= 1) {
        float od = __shfl_xor(bd, off);
        int   on = __shfl_xor(bn, off);
        if (od < bd || (od == bd && on < bn)) { bd = od; bn = on; }
    }
    int idx = bn;

    // outputs
    float4 wa = *(const float4*)(Wf + (size_t)idx * DIM + lane * 8);
    float4 wb = *(const float4*)(Wf + (size_t)idx * DIM + lane * 8 + 4);
    float4 za = *(const float4*)(Zf + (size_t)r   * DIM + lane * 8);
    float4 zb = *(const float4*)(Zf + (size_t)r   * DIM + lane * 8 + 4);
    *(float4*)(outf + (size_t)r * DIM + lane * 8)     = wa;
    *(float4*)(outf + (size_t)r * DIM + lane * 8 + 4) = wb;
    float d0 = za.x - wa.x, d1 = za.y - wa.y, dd2 = za.z - wa.z, d3 = za.w - wa.w;
    float d4 = zb.x - wb.x, d5 = zb.y - wb.y, d6 = zb.z - wb.z, d7 = zb.w - wb.w;
    float ls = d0*d0 + d1*d1 + dd2*dd2 + d3*d3 + d4*d4 + d5*d5 + d6*d6 + d7*d7;
#pragma unroll
    for (int off = 32; off; off >>= 1) ls += __shfl_xor(ls, off);
    if (lane == 0) {
        outf[(size_t)B_ROWS * DIM + r] = (float)idx;
        wsum[wid] = ls;
    }
    __syncthreads();
    if (threadIdx.x == 0) lossp[blockIdx.x] = wsum[0] + wsum[1] + wsum[2] + wsum[3];
}

// ---------- K4: loss reduction ----------
__global__ __launch_bounds__(256) void k_loss(const float* __restrict__ lossp,
                                              float* __restrict__ outf) {
    __shared__ float sm[256];
    float a = 0.f;
    for (int i = threadIdx.x; i < 8192; i += 256) a += lossp[i];
    sm[threadIdx.x] = a;
    __syncthreads();
    for (int s = 128; s; s >>= 1) {
        if (threadIdx.x < s) sm[threadIdx.x] += sm[threadIdx.x + s];
        __syncthreads();
    }
    if (threadIdx.x == 0)
        outf[(size_t)B_ROWS * DIM + B_ROWS] = 1.25f * sm[0] / 16777216.0f;
}

extern "C" void kernel_launch(void* const* d_in, const int* in_sizes, int n_in,
                              void* d_out, int out_size, void* d_ws, size_t ws_size,
                              hipStream_t stream) {
    (void)in_sizes; (void)n_in; (void)out_size; (void)ws_size;
    const float* Zf = (const float*)d_in[0];   // [32768, 512] f32
    const float* Wf = (const float*)d_in[1];   // [8192, 512]  f32
    float* outf = (float*)d_out;               // f32: z_q | indices | loss

    // ws: ww 32KB @0 | zz 128KB @32K | lossp 32KB @160K | part 4MB @192K (total 4.39MB)
    float*  ww    = (float*)d_ws;
    float*  zz    = (float*)((char*)d_ws + 32768);
    float*  lossp = (float*)((char*)d_ws + 163840);
    float2* partp = (float2*)((char*)d_ws + 196608);

    k_pairsq<<<KCODES / 4, 256, 0, stream>>>(Wf, ww, KCODES);
    k_pairsq<<<B_ROWS / 4, 256, 0, stream>>>(Zf, zz, B_ROWS);
    dim3 g2(B_ROWS / 128, SUPERS);
    k_argmin<<<g2, 256, 0, stream>>>(Zf, Wf, ww, partp);
    k_exact<<<B_ROWS / 4, 256, 0, stream>>>(Zf, Wf, partp, zz, ww, outf, lossp);
    k_loss<<<1, 256, 0, stream>>>(lossp, outf);
}

// Round 5
// 760.755 us; speedup vs baseline: 3.2520x; 3.2520x over previous
//
#include <hip/hip_runtime.h>
#include <stdint.h>

// VQ-VAE codebook argmin, f32 in / f32 out.
// R5: pre-split bf16(hi) GEMM (m97-shape: glds16 + 16 MFMA/K-step), packed top-2
// per (row,slice), exact numpy-f32 re-rank of 16 candidates (R4-proven anchor).
// bf16 scratch lives in d_out's z_q region (64 MB) and is overwritten by k_exact.

#define B_ROWS 32768
#define DIM    512
#define KCODES 8192
#define SUPERS 2
#define TILES  32   // per super: 32 tiles * 128 = 4096 codes

typedef short bhalf8_t __attribute__((ext_vector_type(8)));
typedef float f32x4_t  __attribute__((ext_vector_type(4)));

__device__ __forceinline__ float b2f(unsigned short u) {
    return __uint_as_float(((unsigned int)u) << 16);
}
__device__ __forceinline__ unsigned short f2b(float f) {  // RNE
    unsigned int x = __float_as_uint(f);
    return (unsigned short)((x + 0x7FFFu + ((x >> 16) & 1u)) >> 16);
}
__device__ __forceinline__ void gl_lds16(const void* g, void* l) {
    __builtin_amdgcn_global_load_lds(
        (const __attribute__((address_space(1))) unsigned int*)g,
        (__attribute__((address_space(3))) unsigned int*)l, 16, 0, 0);
}

// ---------- K0: f32 -> bf16 (hi only) ----------
__global__ __launch_bounds__(256) void k_split(const float4* __restrict__ src,
                                               ushort4* __restrict__ dst, int n4) {
    int i = blockIdx.x * 256 + threadIdx.x;
    int stride = gridDim.x * 256;
    for (; i < n4; i += stride) {
        float4 v = src[i];
        ushort4 h;
        h.x = f2b(v.x); h.y = f2b(v.y); h.z = f2b(v.z); h.w = f2b(v.w);
        dst[i] = h;
    }
}

// ---------- K1: numpy-pairwise-emulated row sum of squares (R4-proven) ----------
__global__ __launch_bounds__(256) void k_pairsq(const float* __restrict__ X,
                                                float* __restrict__ out, int nrows) {
    int wid = threadIdx.x >> 6, lane = threadIdx.x & 63;
    int r = blockIdx.x * 4 + wid;
    if (r >= nrows) return;
    int b = lane >> 3, j = lane & 7;
    float acc = 0.f;
    if (b < 4) {
        const float* x = X + (size_t)r * DIM + b * 128 + j;
        float v = x[0];
        acc = __fmul_rn(v, v);
        for (int i = 1; i < 16; i++) {
            float w = x[8 * i];
            acc = __fadd_rn(acc, __fmul_rn(w, w));
        }
    }
    float t = __fadd_rn(acc, __shfl_xor(acc, 1));
    t = __fadd_rn(t, __shfl_xor(t, 2));
    t = __fadd_rn(t, __shfl_xor(t, 4));
    float u = __fadd_rn(t, __shfl_xor(t, 8));
    u = __fadd_rn(u, __shfl_xor(u, 16));
    if (lane == 0) out[r] = u;
}

// ---------- K2: bf16 MFMA GEMM + packed top-2/(row,slice) -> top-8/super ----------
// 1D grid of 512 blocks; super = b&1 (XCD round-robin keeps one 4MB W-half per L2).
__global__ __launch_bounds__(256) void k_argmin(const unsigned short* __restrict__ Zh,
                                                const unsigned short* __restrict__ Wh,
                                                const float* __restrict__ ww,
                                                float2* __restrict__ part) {
    __shared__ alignas(16) unsigned char smem[32768];  // staging 16KB; reduce 32KB
    const int tid = threadIdx.x;
    const int lane = tid & 63, w = tid >> 6;
    const int wm = w >> 1, wn = w & 1;
    const int lane15 = lane & 15, q = lane >> 4;
    const int b = blockIdx.x;
    const int super = b & 1;
    const int rb = (b >> 1) * 128;

    uint32_t p1[4][4], p2[4][4];
#pragma unroll
    for (int i = 0; i < 4; i++)
#pragma unroll
        for (int jj = 0; jj < 4; jj++) { p1[i][jj] = 0xFFFFFFFFu; p2[i][jj] = 0xFFFFFFFFu; }

    for (int tl = 0; tl < TILES; ++tl) {
        const int nt = super * 4096 + tl * 128;
        f32x4_t acc[4][4];
#pragma unroll
        for (int i = 0; i < 4; i++)
#pragma unroll
            for (int jj = 0; jj < 4; jj++) acc[i][jj] = (f32x4_t){0.f, 0.f, 0.f, 0.f};

        for (int kb = 0; kb < DIM; kb += 32) {
            __syncthreads();  // prior LDS readers done
#pragma unroll
            for (int l = 0; l < 2; l++) {
                int s = l * 256 + tid;          // 16B segment, lane-contiguous (glds rule)
                int row = s >> 2, seg = s & 3;  // 4 x 16B per 32-bf16 row
                gl_lds16(Zh + (size_t)(rb + row) * DIM + kb + seg * 8, smem +        s * 16);
                gl_lds16(Wh + (size_t)(nt + row) * DIM + kb + seg * 8, smem + 8192 + s * 16);
            }
            __syncthreads();  // vmcnt(0) drain before use

            bhalf8_t af[4], bf[4];
#pragma unroll
            for (int f = 0; f < 4; f++) {
                // A-frag: lane holds A[m=lane&15][k=(lane>>4)*8+j]; B symmetric (B^T form)
                int off = (f * 16 + lane15) * 64 + q * 16;
                af[f] = *(const bhalf8_t*)(smem +        (wm * 4096 + off));
                bf[f] = *(const bhalf8_t*)(smem + 8192 + (wn * 4096 + off));
            }
#pragma unroll
            for (int fm = 0; fm < 4; fm++)
#pragma unroll
                for (int fn = 0; fn < 4; fn++)
                    acc[fm][fn] = __builtin_amdgcn_mfma_f32_16x16x32_bf16(af[fm], bf[fn], acc[fm][fn], 0, 0, 0);
        }

        // epilogue: s' = (ww[n]+0.5) - 2*dot  (positive => float bits monotonic);
        // pack: high-25 bits of score | 7-bit candidate id (tl*4+fn). Strict '<'
        // insert in ascending (tl,fn) => smaller n wins ties within a slice.
        float cb[4];
#pragma unroll
        for (int fn = 0; fn < 4; fn++)
            cb[fn] = ww[nt + wn * 64 + fn * 16 + lane15] + 0.5f;
#pragma unroll
        for (int fm = 0; fm < 4; fm++)
#pragma unroll
            for (int r = 0; r < 4; r++)
#pragma unroll
                for (int fn = 0; fn < 4; fn++) {
                    float sv = fmaf(-2.0f, acc[fm][fn][r], cb[fn]);
                    uint32_t pk = (__float_as_uint(sv) & 0xFFFFFF80u) | (uint32_t)(tl * 4 + fn);
                    if (pk < p1[fm][r]) { p2[fm][r] = p1[fm][r]; p1[fm][r] = pk; }
                    else if (pk < p2[fm][r]) { p2[fm][r] = pk; }
                }
    }

    // per-row top-8 of 64 packed keys via LDS
    __syncthreads();
    uint32_t* keys = (uint32_t*)smem;   // [128 rows][32 slices][2 slots]
#pragma unroll
    for (int fm = 0; fm < 4; fm++)
#pragma unroll
        for (int r = 0; r < 4; r++) {
            int row = wm * 64 + fm * 16 + q * 4 + r;   // C/D row = (lane>>4)*4 + reg
            int slice = wn * 16 + lane15;
            keys[(row * 32 + slice) * 2 + 0] = p1[fm][r];
            keys[(row * 32 + slice) * 2 + 1] = p2[fm][r];
        }
    __syncthreads();
    if (tid < 128) {
        int row = tid;
        int rglob = rb + row;
        for (int s = 0; s < 8; s++) {
            uint32_t bk = 0xFFFFFFFFu; int be = 0;
            for (int e = 0; e < 64; e++) {
                uint32_t k = keys[row * 64 + e];
                if (k < bk) { bk = k; be = e; }
            }
            int slice = be >> 1;
            int id = (int)(bk & 127u);
            int n = super * 4096 + (id >> 2) * 128 + (slice >> 4) * 64 + (id & 3) * 16 + (slice & 15);
            part[((size_t)rglob * SUPERS + super) * 8 + s] =
                make_float2(__uint_as_float(bk), __int_as_float(n));
            keys[row * 64 + be] = 0xFFFFFFFFu;  // consume
        }
    }
}

// ---------- K3: exact numpy-f32 re-rank of 16 candidates, outputs (R4-proven) ----------
__global__ __launch_bounds__(256) void k_exact(const float* __restrict__ Zf,
                                               const float* __restrict__ Wf,
                                               const float2* __restrict__ part,
                                               const float* __restrict__ zz,
                                               const float* __restrict__ ww,
                                               float* __restrict__ outf,
                                               float* __restrict__ lossp) {
    __shared__ float wsum[4];
    int wid = threadIdx.x >> 6, lane = threadIdx.x & 63;
    int r = blockIdx.x * 4 + wid;
    int c = lane >> 2, j = lane & 3;   // candidate 0..15, SSE lane 0..3

    float2 P = part[((size_t)r * SUPERS + (c >> 3)) * 8 + (c & 7)];
    int n = __float_as_int(P.y);
    n = min(max(n, 0), KCODES - 1);

    // numpy einsum baseline-SIMD: 4 stride-4 f32 accumulators (mul+add, no FMA)
    const float* zp = Zf + (size_t)r * DIM + j;
    const float* wp = Wf + (size_t)n * DIM + j;
    float acc = 0.f;
    for (int i = 0; i < 128; i++)
        acc = __fadd_rn(acc, __fmul_rn(zp[4 * i], wp[4 * i]));
    float t = __fadd_rn(acc, __shfl_xor(acc, 1));
    t = __fadd_rn(t, __shfl_xor(t, 2));
    float dot = __shfl(t, c * 4);

    float t1 = __fadd_rn(zz[r], ww[n]);
    float t2 = __fmul_rn(2.0f, dot);
    float d2 = __fadd_rn(t1, -t2);

    float bd = (j == 0) ? d2 : 3.4e38f;
    int   bn = (j == 0) ? n  : 0x7FFFFFFF;
#pragma unroll
    for (int off = 32; off; off >>= 1) {
        float od = __shfl_xor(bd, off);
        int   on = __shfl_xor(bn, off);
        if (od < bd || (od == bd && on < bn)) { bd = od; bn = on; }
    }
    int idx = bn;

    float4 wa = *(const float4*)(Wf + (size_t)idx * DIM + lane * 8);
    float4 wb = *(const float4*)(Wf + (size_t)idx * DIM + lane * 8 + 4);
    float4 za = *(const float4*)(Zf + (size_t)r   * DIM + lane * 8);
    float4 zb = *(const float4*)(Zf + (size_t)r   * DIM + lane * 8 + 4);
    *(float4*)(outf + (size_t)r * DIM + lane * 8)     = wa;
    *(float4*)(outf + (size_t)r * DIM + lane * 8 + 4) = wb;
    float d0 = za.x - wa.x, d1 = za.y - wa.y, dd2 = za.z - wa.z, d3 = za.w - wa.w;
    float d4 = zb.x - wb.x, d5 = zb.y - wb.y, d6 = zb.z - wb.z, d7 = zb.w - wb.w;
    float ls = d0*d0 + d1*d1 + dd2*dd2 + d3*d3 + d4*d4 + d5*d5 + d6*d6 + d7*d7;
#pragma unroll
    for (int off = 32; off; off >>= 1) ls += __shfl_xor(ls, off);
    if (lane == 0) {
        outf[(size_t)B_ROWS * DIM + r] = (float)idx;
        wsum[wid] = ls;
    }
    __syncthreads();
    if (threadIdx.x == 0) lossp[blockIdx.x] = wsum[0] + wsum[1] + wsum[2] + wsum[3];
}

// ---------- K4: loss reduction ----------
__global__ __launch_bounds__(256) void k_loss(const float* __restrict__ lossp,
                                              float* __restrict__ outf) {
    __shared__ float sm[256];
    float a = 0.f;
    for (int i = threadIdx.x; i < 8192; i += 256) a += lossp[i];
    sm[threadIdx.x] = a;
    __syncthreads();
    for (int s = 128; s; s >>= 1) {
        if (threadIdx.x < s) sm[threadIdx.x] += sm[threadIdx.x + s];
        __syncthreads();
    }
    if (threadIdx.x == 0)
        outf[(size_t)B_ROWS * DIM + B_ROWS] = 1.25f * sm[0] / 16777216.0f;
}

extern "C" void kernel_launch(void* const* d_in, const int* in_sizes, int n_in,
                              void* d_out, int out_size, void* d_ws, size_t ws_size,
                              hipStream_t stream) {
    (void)in_sizes; (void)n_in; (void)out_size; (void)ws_size;
    const float* Zf = (const float*)d_in[0];   // [32768, 512] f32
    const float* Wf = (const float*)d_in[1];   // [8192, 512]  f32
    float* outf = (float*)d_out;               // f32: z_q | indices | loss

    // bf16 scratch inside d_out's z_q region (64 MB): Zh 32MB @0 | Wh 8MB @32MB.
    // k_exact overwrites it with the final z_q (k_argmin has completed by then).
    unsigned short* Zh = (unsigned short*)d_out;
    unsigned short* Wh = (unsigned short*)((char*)d_out + (32ull << 20));

    // ws (4.39 MB, proven): ww 32KB @0 | zz 128KB @32K | lossp 32KB @160K | part 4MB @192K
    float*  ww    = (float*)d_ws;
    float*  zz    = (float*)((char*)d_ws + 32768);
    float*  lossp = (float*)((char*)d_ws + 163840);
    float2* partp = (float2*)((char*)d_ws + 196608);

    k_split<<<1024, 256, 0, stream>>>((const float4*)Zf, (ushort4*)Zh, B_ROWS * DIM / 4);
    k_split<<<512,  256, 0, stream>>>((const float4*)Wf, (ushort4*)Wh, KCODES * DIM / 4);
    k_pairsq<<<KCODES / 4, 256, 0, stream>>>(Wf, ww, KCODES);
    k_pairsq<<<B_ROWS / 4, 256, 0, stream>>>(Zf, zz, B_ROWS);
    k_argmin<<<(B_ROWS / 128) * SUPERS, 256, 0, stream>>>(Zh, Wh, ww, partp);
    k_exact<<<B_ROWS / 4, 256, 0, stream>>>(Zf, Wf, partp, zz, ww, outf, lossp);
    k_loss<<<1, 256, 0, stream>>>(lossp, outf);
}